// Round 6
// baseline (561.010 us; speedup 1.0000x reference)
//
#include <hip/hip_runtime.h>
#include <hip/hip_fp16.h>
#include <hip/hip_cooperative_groups.h>

namespace cg = cooperative_groups;

// GCN 2-layer inference on MI355X — single cooperative mega-kernel.
// Round-6: fuse memset+5 kernels' pipeline into one dispatch (6 launches were
// ~105us controllable vs ~50us of modeled kernel work -> launch/serialization
// overhead). lin1 stores RAW x@W1 (fp16); dis[src]/dis[dst] are folded into
// the gather phases, so CSR build and lin1 overlap in phase 1.
//
// Phases (grid.sync between):
//  P1a: bucket-fill edges (dst<<16|src) into 256-node bucket slabs (LDS hist,
//       one global atomic reservation per touched bucket per block)
//  P1b: g_raw[n][f] = (x[n,:]@W1[:,f])  (fp16)
//  P2:  per-bucket: ebase=sum(bcnt[<b]); node hist; LDS scan -> rowptr,dis;
//       counting-sort -> csr (ushort local src ids)
//  P3:  wave-per-node: acc=dis[n]*g[n]+sum dis[s]*g[s]; h=relu(dis*acc+b1);
//       q=(h.W2)*dis
//  P4:  thread-per-node: out=sigmoid(dis*(q[n]+sum q[s])+b2)

#define FH 64
#define NPB 256      // nodes per bucket (== block size; thread-indexed LDS)
#define MAXBK 512    // LDS bound on bucket count (N <= 131072)
#define CHB 2048     // edges per fill chunk
#define BCAP 8192    // slots per bucket slab (mean 4096 + ~64 sigma)
#define GRID_BLKS 1024

struct Params {
    const int* src; const int* dst;
    const float* x; const float* W1; const float* b1; const float* W2; const float* b2;
    float* out;
    int* rowptr; float* dis; unsigned short* csr; __half* g; float* q;
    int* bcnt; unsigned int* ebuf;
    int N, E, nbk, nbe, npass;
};

__global__ void __launch_bounds__(256) k_mega(Params p) {
    cg::grid_group grid = cg::this_grid();
    const int t = threadIdx.x;
    const int bid = blockIdx.x;
    const int nb = gridDim.x;

    __shared__ int h[MAXBK];
    __shared__ int resv[MAXBK];
    __shared__ int sc[NPB];
    __shared__ int ff[NPB];
    __shared__ float sW[4 * FH];
    __shared__ int sbase;

    sW[t] = p.W1[t];  // W1 is exactly 4*64 = 256 floats
    __syncthreads();

    // ---- P1a: bucket fill ----
    for (int c = bid; c < p.nbe; c += nb) {
        for (int i = t; i < p.nbk; i += 256) h[i] = 0;
        __syncthreads();
        int base = c * CHB, end = min(base + CHB, p.E);
        for (int e = base + t; e < end; e += 256)
            atomicAdd(&h[p.dst[e] >> 8], 1);
        __syncthreads();
        for (int i = t; i < p.nbk; i += 256) {
            int cc = h[i];
            resv[i] = cc ? atomicAdd(&p.bcnt[i], cc) : 0;
            h[i] = 0;  // reuse as local cursor
        }
        __syncthreads();
        for (int e = base + t; e < end; e += 256) {
            int d = p.dst[e];
            int b = d >> 8;
            int idx = resv[b] + atomicAdd(&h[b], 1);
            if (idx < BCAP)
                p.ebuf[(size_t)b * BCAP + idx] = ((unsigned)d << 16) | (unsigned)p.src[e];
        }
        __syncthreads();
    }

    // ---- P1b: lin1 (raw x@W1 -> fp16) ----
    for (int pass = bid; pass < p.npass; pass += nb) {
        int node = pass * 4 + (t >> 6), f = t & 63;
        if (node < p.N) {
            float4 xv = *reinterpret_cast<const float4*>(p.x + (size_t)node * 4);
            float v = xv.x * sW[f] + xv.y * sW[FH + f] + xv.z * sW[2 * FH + f] + xv.w * sW[3 * FH + f];
            p.g[(size_t)node * FH + f] = __float2half_rn(v);
        }
    }

    grid.sync();

    // ---- P2: per-bucket finish ----
    for (int b = bid; b < p.nbk; b += nb) {
        int s = 0;
        for (int i = t; i < b; i += 256) s += p.bcnt[i];
        sc[t] = s;
        __syncthreads();
        for (int off = 128; off; off >>= 1) {
            if (t < off) sc[t] += sc[t + off];
            __syncthreads();
        }
        if (t == 0) sbase = sc[0];
        __syncthreads();
        int ebase = sbase;
        int cnt = min(p.bcnt[b], BCAP);
        const unsigned int* eb = p.ebuf + (size_t)b * BCAP;
        ff[t] = 0;
        __syncthreads();
        for (int j = t; j < cnt; j += 256)
            atomicAdd(&ff[(eb[j] >> 16) & (NPB - 1)], 1);
        __syncthreads();
        int myc = ff[t];
        sc[t] = myc;
        __syncthreads();
        for (int off = 1; off < NPB; off <<= 1) {
            int add = (t >= off) ? sc[t - off] : 0;
            __syncthreads();
            sc[t] += add;
            __syncthreads();
        }
        int ex = ebase + sc[t] - myc;
        int node = b * NPB + t;
        if (node < p.N) {
            p.rowptr[node] = ex;
            p.dis[node] = rsqrtf((float)(myc + 1));
        }
        if (node == p.N - 1) p.rowptr[p.N] = ex + myc;
        __syncthreads();
        ff[t] = ex;  // reuse as fill cursors
        __syncthreads();
        for (int j = t; j < cnt; j += 256) {
            unsigned int pe = eb[j];
            int pos = atomicAdd(&ff[(pe >> 16) & (NPB - 1)], 1);
            p.csr[pos] = (unsigned short)(pe & 0xffffu);
        }
        __syncthreads();
    }

    grid.sync();

    // ---- P3: layer1, wave-per-node ----
    {
        int f = t & 63;
        int w = (bid << 2) + (t >> 6);
        int nw = nb << 2;
        for (int node = w; node < p.N; node += nw) {
            int rs = p.rowptr[node], re = p.rowptr[node + 1];
            float dn = p.dis[node];
            float acc = dn * __half2float(p.g[(size_t)node * FH + f]);  // self loop
            int j = rs;
            for (; j + 3 < re; j += 4) {
                int s0 = p.csr[j], s1 = p.csr[j + 1], s2 = p.csr[j + 2], s3 = p.csr[j + 3];
                acc += p.dis[s0] * __half2float(p.g[(size_t)s0 * FH + f]);
                acc += p.dis[s1] * __half2float(p.g[(size_t)s1 * FH + f]);
                acc += p.dis[s2] * __half2float(p.g[(size_t)s2 * FH + f]);
                acc += p.dis[s3] * __half2float(p.g[(size_t)s3 * FH + f]);
            }
            for (; j < re; ++j) {
                int s0 = p.csr[j];
                acc += p.dis[s0] * __half2float(p.g[(size_t)s0 * FH + f]);
            }
            float hh = fmaxf(dn * acc + p.b1[f], 0.0f);
            float v = hh * p.W2[f];
            #pragma unroll
            for (int off = 32; off; off >>= 1) v += __shfl_xor(v, off, 64);
            if (f == 0) p.q[node] = v * dn;
        }
    }

    grid.sync();

    // ---- P4: layer2 + sigmoid ----
    for (int i = bid * 256 + t; i < p.N; i += nb * 256) {
        int rs = p.rowptr[i], re = p.rowptr[i + 1];
        float acc = p.q[i];  // self loop
        int j = rs;
        for (; j + 3 < re; j += 4)
            acc += p.q[p.csr[j]] + p.q[p.csr[j + 1]] + p.q[p.csr[j + 2]] + p.q[p.csr[j + 3]];
        for (; j < re; ++j) acc += p.q[p.csr[j]];
        float v = p.dis[i] * acc + p.b2[0];
        p.out[i] = 1.0f / (1.0f + __expf(-v));
    }
}

extern "C" void kernel_launch(void* const* d_in, const int* in_sizes, int n_in,
                              void* d_out, int out_size, void* d_ws, size_t ws_size,
                              hipStream_t stream) {
    const float* x   = (const float*)d_in[0];
    const int*   ei  = (const int*)d_in[1];
    const float* W1  = (const float*)d_in[2];
    const float* b1  = (const float*)d_in[3];
    const float* W2  = (const float*)d_in[4];
    const float* b2  = (const float*)d_in[5];
    float* out = (float*)d_out;

    int N = in_sizes[0] / 4;
    int E = in_sizes[1] / 2;
    const int* src = ei;
    const int* dst = ei + E;
    int nbk = (N + NPB - 1) / NPB;   // 196 for N=50000
    int nbe = (E + CHB - 1) / CHB;   // 391 for E=800000

    // workspace layout (256B aligned)
    char* ws = (char*)d_ws;
    size_t off = 0;
    auto alloc = [&](size_t bytes) {
        void* p = ws + off;
        off = (off + bytes + 255) & ~(size_t)255;
        return p;
    };
    int*            rowptr = (int*)alloc((size_t)(N + 1) * 4);
    float*          dis    = (float*)alloc((size_t)N * 4);
    unsigned short* csr    = (unsigned short*)alloc((size_t)E * 2);
    __half*         g      = (__half*)alloc((size_t)N * FH * 2);
    float*          q      = (float*)alloc((size_t)N * 4);
    int*            bcnt   = (int*)alloc((size_t)MAXBK * 4);
    unsigned int*   ebuf   = (unsigned int*)alloc((size_t)nbk * BCAP * 4);
    (void)ws_size;

    hipMemsetAsync(bcnt, 0, (size_t)MAXBK * 4, stream);

    Params p{src, dst, x, W1, b1, W2, b2, out,
             rowptr, dis, csr, g, q, bcnt, ebuf,
             N, E, nbk, nbe, (N + 3) / 4};
    void* args[] = {&p};
    hipLaunchCooperativeKernel((void*)k_mega, dim3(GRID_BLKS), dim3(256),
                               args, 0, stream);
}

// Round 7
// 140.710 us; speedup vs baseline: 3.9870x; 3.9870x over previous
//
#include <hip/hip_runtime.h>
#include <hip/hip_fp16.h>

// GCN 2-layer inference on MI355X — CSR-gather, bucket CSR build.
// Round-7: revert cooperative mega-kernel (grid.sync cost ~430us on 8-XCD
// gfx950). Back to round-5 stream-ordered pipeline, with lin1 fused into the
// bucket-fill dispatch (independent work, one launch fewer). lin1 stores RAW
// x@W1 (fp16); dis[src] is folded into the layer1 gather.
//
// Math: cnt[n] = indegree(n); deg = cnt+1 (self loop); dis = rsqrt(deg)
//   g[n][f]  = (x@W1)[n][f]                      (raw, fp16)
//   h[n][f]  = relu( dis[n]*(dis[n]*g[n][f] + sum_s dis[s]*g[s][f]) + b1[f] )
//   q[n]     = (h[n] . W2) * dis[n]
//   out[n]   = sigmoid( dis[n] * (q[n] + sum_s q[s]) + b2 )

#define FH 64
#define NPB 256      // nodes per bucket (== block size; thread-indexed LDS)
#define MAXBK 512    // LDS bound on bucket count (N <= 131072)
#define CHB 2048     // edges per fill chunk
#define BCAP 8192    // slots per bucket slab (mean 4096 + ~64 sigma)
#define LIN1_BLKS 2048

// Fused dispatch: blocks [0, nbe) do bucket-fill; blocks [nbe, nbe+LIN1_BLKS)
// do lin1 (grid-strided over nodes).
__global__ void k_fill_lin1(const int* __restrict__ src, const int* __restrict__ dst,
                            int* __restrict__ bcnt, unsigned int* __restrict__ ebuf,
                            const float* __restrict__ x, const float* __restrict__ W1,
                            __half* __restrict__ g,
                            int E, int nbk, int nbe, int N) {
    int t = threadIdx.x;
    if ((int)blockIdx.x < nbe) {
        // ---- bucket fill ----
        __shared__ int h[MAXBK];
        __shared__ int resv[MAXBK];
        for (int i = t; i < nbk; i += 256) h[i] = 0;
        __syncthreads();
        int base = blockIdx.x * CHB;
        int end = min(base + CHB, E);
        for (int e = base + t; e < end; e += 256)
            atomicAdd(&h[dst[e] >> 8], 1);
        __syncthreads();
        for (int i = t; i < nbk; i += 256) {
            int c = h[i];
            resv[i] = c ? atomicAdd(&bcnt[i], c) : 0;
            h[i] = 0;  // reuse as local fill cursor
        }
        __syncthreads();
        for (int e = base + t; e < end; e += 256) {
            int d = dst[e];
            int b = d >> 8;
            int idx = resv[b] + atomicAdd(&h[b], 1);
            if (idx < BCAP)
                ebuf[(size_t)b * BCAP + idx] = ((unsigned)d << 16) | (unsigned)src[e];
        }
    } else {
        // ---- lin1: g = x @ W1 (raw, fp16) ----
        __shared__ float sW[4 * FH];
        sW[t] = W1[t];
        __syncthreads();
        int pass0 = (int)blockIdx.x - nbe;
        int npass = (N + 3) / 4;
        int f = t & 63;
        for (int pass = pass0; pass < npass; pass += LIN1_BLKS) {
            int node = pass * 4 + (t >> 6);
            if (node < N) {
                float4 xv = *reinterpret_cast<const float4*>(x + (size_t)node * 4);
                float v = xv.x * sW[f] + xv.y * sW[FH + f] + xv.z * sW[2 * FH + f] + xv.w * sW[3 * FH + f];
                g[(size_t)node * FH + f] = __float2half_rn(v);
            }
        }
    }
}

// One block per bucket: ebase = sum(bcnt[i<b]); node hist; LDS scan ->
// rowptr, dis; counting-sort placement -> csr (ushort src ids).
__global__ void k_bkt_finish(const unsigned int* __restrict__ ebuf,
                             const int* __restrict__ bcnt,
                             int* __restrict__ rowptr, float* __restrict__ dis,
                             unsigned short* __restrict__ csr, int N) {
    __shared__ int sc[NPB];
    __shared__ int f[NPB];
    __shared__ int sbase;
    int b = blockIdx.x, t = threadIdx.x;
    int s = 0;
    for (int i = t; i < b; i += 256) s += bcnt[i];
    sc[t] = s;
    __syncthreads();
    for (int off = 128; off; off >>= 1) {
        if (t < off) sc[t] += sc[t + off];
        __syncthreads();
    }
    if (t == 0) sbase = sc[0];
    __syncthreads();
    int ebase = sbase;
    int cnt = min(bcnt[b], BCAP);
    const unsigned int* eb = ebuf + (size_t)b * BCAP;
    f[t] = 0;
    __syncthreads();
    for (int j = t; j < cnt; j += 256)
        atomicAdd(&f[(eb[j] >> 16) & (NPB - 1)], 1);
    __syncthreads();
    int myc = f[t];
    sc[t] = myc;
    __syncthreads();
    for (int off = 1; off < NPB; off <<= 1) {
        int add = (t >= off) ? sc[t - off] : 0;
        __syncthreads();
        sc[t] += add;
        __syncthreads();
    }
    int ex = ebase + sc[t] - myc;  // rowptr for this node
    int node = b * NPB + t;
    if (node < N) {
        rowptr[node] = ex;
        dis[node] = rsqrtf((float)(myc + 1));
    }
    if (node == N - 1) rowptr[N] = ex + myc;
    __syncthreads();
    f[t] = ex;  // reuse as fill cursors
    __syncthreads();
    for (int j = t; j < cnt; j += 256) {
        unsigned int pe = eb[j];
        int p = atomicAdd(&f[(pe >> 16) & (NPB - 1)], 1);
        csr[p] = (unsigned short)(pe & 0xffffu);
    }
}

// One wave per node: acc = dis[n]*g[n] + sum dis[s]*g[s]; relu + W2 dot -> q.
__global__ void k_layer1(const int* __restrict__ rowptr, const unsigned short* __restrict__ csr,
                         const __half* __restrict__ g, const float* __restrict__ dis,
                         const float* __restrict__ b1, const float* __restrict__ W2,
                         float* __restrict__ q, int n) {
    int t = threadIdx.x;
    int node = blockIdx.x * 4 + (t >> 6);
    int f = t & 63;
    if (node >= n) return;
    int rs = rowptr[node], re = rowptr[node + 1];
    float dn = dis[node];
    float acc = dn * __half2float(g[(size_t)node * FH + f]);  // self loop
    int j = rs;
    for (; j + 3 < re; j += 4) {
        int s0 = csr[j], s1 = csr[j + 1], s2 = csr[j + 2], s3 = csr[j + 3];
        acc += dis[s0] * __half2float(g[(size_t)s0 * FH + f]);
        acc += dis[s1] * __half2float(g[(size_t)s1 * FH + f]);
        acc += dis[s2] * __half2float(g[(size_t)s2 * FH + f]);
        acc += dis[s3] * __half2float(g[(size_t)s3 * FH + f]);
    }
    for (; j < re; ++j) {
        int s0 = csr[j];
        acc += dis[s0] * __half2float(g[(size_t)s0 * FH + f]);
    }
    float h = fmaxf(dn * acc + b1[f], 0.0f);
    float v = h * W2[f];
    #pragma unroll
    for (int off = 32; off; off >>= 1) v += __shfl_xor(v, off, 64);
    if (f == 0) q[node] = v * dn;
}

// One thread per node: gather q of in-neighbors, fuse sigmoid.
__global__ void k_layer2(const int* __restrict__ rowptr, const unsigned short* __restrict__ csr,
                         const float* __restrict__ q, const float* __restrict__ dis,
                         const float* __restrict__ b2, float* __restrict__ out, int n) {
    int i = blockIdx.x * blockDim.x + threadIdx.x;
    if (i >= n) return;
    int rs = rowptr[i], re = rowptr[i + 1];
    float acc = q[i];  // self loop
    int j = rs;
    for (; j + 3 < re; j += 4)
        acc += q[csr[j]] + q[csr[j + 1]] + q[csr[j + 2]] + q[csr[j + 3]];
    for (; j < re; ++j) acc += q[csr[j]];
    float v = dis[i] * acc + b2[0];
    out[i] = 1.0f / (1.0f + __expf(-v));
}

extern "C" void kernel_launch(void* const* d_in, const int* in_sizes, int n_in,
                              void* d_out, int out_size, void* d_ws, size_t ws_size,
                              hipStream_t stream) {
    const float* x   = (const float*)d_in[0];
    const int*   ei  = (const int*)d_in[1];
    const float* W1  = (const float*)d_in[2];
    const float* b1  = (const float*)d_in[3];
    const float* W2  = (const float*)d_in[4];
    const float* b2  = (const float*)d_in[5];
    float* out = (float*)d_out;

    int N = in_sizes[0] / 4;
    int E = in_sizes[1] / 2;
    const int* src = ei;
    const int* dst = ei + E;
    int nbk = (N + NPB - 1) / NPB;   // 196 for N=50000
    int nbe = (E + CHB - 1) / CHB;   // 391 for E=800000

    // workspace layout (256B aligned)
    char* ws = (char*)d_ws;
    size_t off = 0;
    auto alloc = [&](size_t bytes) {
        void* p = ws + off;
        off = (off + bytes + 255) & ~(size_t)255;
        return p;
    };
    int*            rowptr = (int*)alloc((size_t)(N + 1) * 4);
    float*          dis    = (float*)alloc((size_t)N * 4);
    unsigned short* csr    = (unsigned short*)alloc((size_t)E * 2);
    __half*         g      = (__half*)alloc((size_t)N * FH * 2);
    float*          q      = (float*)alloc((size_t)N * 4);
    int*            bcnt   = (int*)alloc((size_t)MAXBK * 4);
    unsigned int*   ebuf   = (unsigned int*)alloc((size_t)nbk * BCAP * 4);
    (void)ws_size;

    hipMemsetAsync(bcnt, 0, (size_t)MAXBK * 4, stream);

    k_fill_lin1<<<nbe + LIN1_BLKS, 256, 0, stream>>>(src, dst, bcnt, ebuf,
                                                     x, W1, g, E, nbk, nbe, N);
    k_bkt_finish<<<nbk, 256, 0, stream>>>(ebuf, bcnt, rowptr, dis, csr, N);
    k_layer1<<<(N + 3) / 4, 256, 0, stream>>>(rowptr, csr, g, dis, b1, W2, q, N);
    k_layer2<<<(N + 255) / 256, 256, 0, stream>>>(rowptr, csr, q, dis, b2, out, N);
}